// Round 3
// baseline (1395.634 us; speedup 1.0000x reference)
//
#include <hip/hip_runtime.h>
#include <hip/hip_bf16.h>

#define N_NODES 400000
#define N_EDGES 1600000
#define N_GRAPHS 16384

__device__ __forceinline__ float rlane(float x, int k) {
    return __int_as_float(__builtin_amdgcn_readlane(__float_as_int(x), k));
}

// ---- fused histogram: edge degree + batch counts ----
__global__ void k_hist(const int* __restrict__ rows, const int* __restrict__ batch,
                       int* __restrict__ degcnt, int* __restrict__ gcnt, int E, int N) {
    int t = blockIdx.x * blockDim.x + threadIdx.x;
    if (t < E) atomicAdd(&degcnt[rows[t]], 1);
    if (t < N) atomicAdd(&gcnt[batch[t]], 1);
}

// ---- scan step 1: per-block sums over concat(degcnt, gcnt) ----
__global__ void k_scan_blocksum(const int* __restrict__ src, int* __restrict__ bsum, int n) {
    __shared__ int s[256];
    int t = threadIdx.x;
    int idx = blockIdx.x * 256 + t;
    int v = idx < n ? src[idx] : 0;
    s[t] = v; __syncthreads();
    for (int off = 128; off > 0; off >>= 1) {
        if (t < off) s[t] += s[t + off];
        __syncthreads();
    }
    if (t == 0) bsum[blockIdx.x] = s[0];
}

// ---- scan step 2: single-block exclusive scan of block sums ----
__global__ void k_scan_single(const int* __restrict__ src, int* __restrict__ dst, int n) {
    __shared__ int s[256];
    __shared__ int carry_s;
    int t = threadIdx.x;
    if (t == 0) carry_s = 0;
    __syncthreads();
    for (int base = 0; base < n; base += 256) {
        int idx = base + t;
        int v = idx < n ? src[idx] : 0;
        s[t] = v; __syncthreads();
        for (int off = 1; off < 256; off <<= 1) {
            int x = (t >= off) ? s[t - off] : 0;
            __syncthreads();
            s[t] += x;
            __syncthreads();
        }
        int incl = s[t];
        int carry = carry_s;
        if (idx < n) dst[idx] = carry + incl - v;
        __syncthreads();
        if (t == 255) carry_s = carry + incl;
        __syncthreads();
    }
}

// ---- scan step 3: final exclusive scan; write row_ptr[N+1]/cursor/dinv/gstart ----
__global__ void k_scan_final(const int* __restrict__ src, const int* __restrict__ boffs,
                             int* __restrict__ row_ptr, int* __restrict__ cursor,
                             float* __restrict__ dinv, int* __restrict__ gstart,
                             int n, int N, int E) {
    __shared__ int s[256];
    int t = threadIdx.x;
    int idx = blockIdx.x * 256 + t;
    int v = idx < n ? src[idx] : 0;
    s[t] = v; __syncthreads();
    for (int off = 1; off < 256; off <<= 1) {
        int x = (t >= off) ? s[t - off] : 0;
        __syncthreads();
        s[t] += x;
        __syncthreads();
    }
    if (idx < n) {
        int excl = boffs[blockIdx.x] + s[t] - v;
        if (idx < N) {
            row_ptr[idx] = excl;
            cursor[idx] = excl;
            dinv[idx] = rsqrtf((float)v + 1.0f);
        } else {
            if (idx == N) row_ptr[N] = E;
            gstart[idx - N] = excl - E;
        }
    }
}

// ---- scatter edge cols into CSR (4B payload only; dinv folded into GEMM) ----
__global__ void k_scatter(const int* __restrict__ rows, const int* __restrict__ colsIn,
                          int* __restrict__ cursor, int* __restrict__ colsOut, int E) {
    int e = blockIdx.x * blockDim.x + threadIdx.x;
    if (e < E) {
        int r = rows[e];
        int pos = atomicAdd(&cursor[r], 1);
        colsOut[pos] = colsIn[e];
    }
}

// ---- GEMM: out[i][lane] = dinv[i] * sum_k in[i][k] * W[k][lane] ----
// Row index is wave-uniform -> input row loads become s_load (SGPR broadcast);
// W column (64 floats) lives in VGPRs; inner op is v_fma acc, s_k, v_wk.
template <int IN_D>
__global__ __launch_bounds__(256, 4) void k_gemm(
        const float* __restrict__ in, const float* __restrict__ W,
        const float* __restrict__ dinv, float* __restrict__ out, int N) {
    const int lane = threadIdx.x & 63;
    int wid = (blockIdx.x * blockDim.x + threadIdx.x) >> 6;
    wid = __builtin_amdgcn_readfirstlane(wid);
    const int nw = (gridDim.x * blockDim.x) >> 6;
    const int chunk = (N + nw - 1) / nw;
    const int i0 = wid * chunk;
    const int i1 = min(i0 + chunk, N);

    float w_reg[IN_D];
#pragma unroll
    for (int k = 0; k < IN_D; ++k) {
        w_reg[k] = W[k * 64 + lane];
        asm volatile("" : "+v"(w_reg[k]));
    }

    for (int i = i0; i < i1; ++i) {
        const float* rp = in + (size_t)i * IN_D;   // uniform -> scalar loads
        const float di = dinv[i];                  // uniform
        float a0 = 0.f, a1 = 0.f, a2 = 0.f, a3 = 0.f;
#pragma unroll
        for (int k = 0; k < IN_D; k += 4) {
            a0 = fmaf(rp[k + 0], w_reg[k + 0], a0);
            a1 = fmaf(rp[k + 1], w_reg[k + 1], a1);
            a2 = fmaf(rp[k + 2], w_reg[k + 2], a2);
            a3 = fmaf(rp[k + 3], w_reg[k + 3], a3);
        }
        out[(size_t)i * 64 + lane] = di * ((a0 + a1) + (a2 + a3));
    }
}

// ---- aggregation: h[i][lane] = relu( di*(M[i] + sum_{j in N(i)} M[j]) + b ) ----
// One wave per node; cols/row_ptr/dinv wave-uniform (scalar loads); per edge:
// one coalesced 256B row load + one v_add. 4 gathers in flight per batch.
__global__ __launch_bounds__(256, 8) void k_agg(
        const float* __restrict__ M, const float* __restrict__ bias,
        const int* __restrict__ row_ptr, const int* __restrict__ cols,
        const float* __restrict__ dinv, float* __restrict__ out, int N) {
    const int lane = threadIdx.x & 63;
    int wid = (blockIdx.x * blockDim.x + threadIdx.x) >> 6;
    wid = __builtin_amdgcn_readfirstlane(wid);
    const int nw = (gridDim.x * blockDim.x) >> 6;
    const int chunk = (N + nw - 1) / nw;
    const int i0 = wid * chunk;
    const int i1 = min(i0 + chunk, N);
    const float b = bias[lane];

    for (int i = i0; i < i1; ++i) {
        const int s0 = row_ptr[i];
        const int s1 = row_ptr[i + 1];
        const float di = dinv[i];
        float acc = M[(size_t)i * 64 + lane];  // self term
        int e = s0;
        for (; e + 4 <= s1; e += 4) {
            int c0 = cols[e + 0];
            int c1 = cols[e + 1];
            int c2 = cols[e + 2];
            int c3 = cols[e + 3];
            float v0 = M[(size_t)c0 * 64 + lane];
            float v1 = M[(size_t)c1 * 64 + lane];
            float v2 = M[(size_t)c2 * 64 + lane];
            float v3 = M[(size_t)c3 * 64 + lane];
            acc += ((v0 + v1) + (v2 + v3));
        }
        for (; e < s1; ++e) {
            acc += M[(size_t)cols[e] * 64 + lane];
        }
        float h = fmaxf(fmaf(di, acc, b), 0.0f);
        out[(size_t)i * 64 + lane] = h;
    }
}

// ---- pooling: wave per graph, 4 nodes in flight (16-lane float4 subgroups) ----
__global__ void k_pool(const float* __restrict__ h, const int* __restrict__ gstart,
                       const int* __restrict__ gcnt, float* __restrict__ pooled, int G) {
    const int lane = threadIdx.x & 63;
    const int c = lane & 15;
    const int g = lane >> 4;
    const int wid = (blockIdx.x * blockDim.x + threadIdx.x) >> 6;
    const int nw = (gridDim.x * blockDim.x) >> 6;
    const float NEG = -3.402823466e38f;
    for (int gr = wid; gr < G; gr += nw) {
        int gs = gstart[gr], gc = gcnt[gr];
        float4 sum = {0.f, 0.f, 0.f, 0.f};
        float4 mx = {NEG, NEG, NEG, NEG};
        const float* base = h + (size_t)gs * 64 + 4 * c;
        for (int p = g; p < gc; p += 4) {
            float4 v = *(const float4*)(base + (size_t)p * 64);
            sum.x += v.x; sum.y += v.y; sum.z += v.z; sum.w += v.w;
            mx.x = fmaxf(mx.x, v.x); mx.y = fmaxf(mx.y, v.y);
            mx.z = fmaxf(mx.z, v.z); mx.w = fmaxf(mx.w, v.w);
        }
#pragma unroll
        for (int s = 16; s < 64; s <<= 1) {
            sum.x += __shfl_xor(sum.x, s); sum.y += __shfl_xor(sum.y, s);
            sum.z += __shfl_xor(sum.z, s); sum.w += __shfl_xor(sum.w, s);
            mx.x = fmaxf(mx.x, __shfl_xor(mx.x, s));
            mx.y = fmaxf(mx.y, __shfl_xor(mx.y, s));
            mx.z = fmaxf(mx.z, __shfl_xor(mx.z, s));
            mx.w = fmaxf(mx.w, __shfl_xor(mx.w, s));
        }
        float inv = 1.0f / fmaxf((float)gc, 1.0f);
        float4 mean = {sum.x * inv, sum.y * inv, sum.z * inv, sum.w * inv};
        float4 mxo = gc > 0 ? mx : make_float4(0.f, 0.f, 0.f, 0.f);
        if (lane < 16) {
            *(float4*)(pooled + (size_t)gr * 128 + 4 * c) = mean;
            *(float4*)(pooled + (size_t)gr * 128 + 64 + 4 * c) = mxo;
        }
    }
}

// ---- predictor: fused meta-encoder + MLP head; one wave per graph ----
__global__ void k_pred(const float* __restrict__ pooled, const float* __restrict__ metadata,
                       const int* __restrict__ species, const float* __restrict__ emb,
                       const float* __restrict__ Wm, const float* __restrict__ bm,
                       const float* __restrict__ Wp1, const float* __restrict__ bp1,
                       const float* __restrict__ Wp2, const float* __restrict__ bp2,
                       float* __restrict__ out, int G) {
    __shared__ float Wp1L[208 * 64];
    __shared__ float WmL[16 * 64];
    __shared__ float bp1L[64], bmL[64], Wp2L[64];
    int t = threadIdx.x;
    for (int idx = t; idx < 208 * 64; idx += blockDim.x) Wp1L[idx] = Wp1[idx];
    for (int idx = t; idx < 16 * 64; idx += blockDim.x) WmL[idx] = Wm[idx];
    if (t < 64) {
        bp1L[t] = bp1[t];
        bmL[t] = bm[t];
        Wp2L[t] = Wp2[t];
    }
    __syncthreads();
    const float bp2v = bp2[0];
    const int lane = t & 63;
    const int wid = (blockIdx.x * blockDim.x + t) >> 6;
    const int nw = (gridDim.x * blockDim.x) >> 6;
    for (int g = wid; g < G; g += nw) {
        float f0 = pooled[g * 128 + lane];        // mean
        float f1 = pooled[g * 128 + 64 + lane];   // max
        float md = lane < 16 ? metadata[g * 16 + lane] : 0.0f;
        float m = bmL[lane];
#pragma unroll
        for (int k = 0; k < 16; ++k) m = fmaf(rlane(md, k), WmL[k * 64 + lane], m);
        float f2 = fmaxf(m, 0.0f);                // meta relu
        int sid = species[g];
        float f3 = lane < 16 ? emb[sid * 16 + lane] : 0.0f;  // species emb
        float tacc = bp1L[lane];
#pragma unroll
        for (int k = 0; k < 64; ++k) tacc = fmaf(rlane(f0, k), Wp1L[k * 64 + lane], tacc);
#pragma unroll
        for (int k = 0; k < 64; ++k) tacc = fmaf(rlane(f1, k), Wp1L[(64 + k) * 64 + lane], tacc);
#pragma unroll
        for (int k = 0; k < 64; ++k) tacc = fmaf(rlane(f2, k), Wp1L[(128 + k) * 64 + lane], tacc);
#pragma unroll
        for (int k = 0; k < 16; ++k) tacc = fmaf(rlane(f3, k), Wp1L[(192 + k) * 64 + lane], tacc);
        tacc = fmaxf(tacc, 0.0f);
        float r = tacc * Wp2L[lane];
        for (int off = 32; off > 0; off >>= 1) r += __shfl_down(r, off);
        if (lane == 0) out[g] = r + bp2v;
    }
}

extern "C" void kernel_launch(void* const* d_in, const int* in_sizes, int n_in,
                              void* d_out, int out_size, void* d_ws, size_t ws_size,
                              hipStream_t stream) {
    const int N = N_NODES, E = N_EDGES, G = N_GRAPHS;
    const int NT = N + G;

    const float* x        = (const float*)d_in[0];
    const float* metadata = (const float*)d_in[1];
    const int*   ei       = (const int*)d_in[2];
    const int*   batch    = (const int*)d_in[3];
    const int*   species  = (const int*)d_in[4];
    const float* W1 = (const float*)d_in[5];
    const float* b1 = (const float*)d_in[6];
    const float* W2 = (const float*)d_in[7];
    const float* b2 = (const float*)d_in[8];
    const float* W3 = (const float*)d_in[9];
    const float* b3 = (const float*)d_in[10];
    const float* Wm = (const float*)d_in[11];
    const float* bm = (const float*)d_in[12];
    const float* emb = (const float*)d_in[13];
    const float* Wp1 = (const float*)d_in[14];
    const float* bp1 = (const float*)d_in[15];
    const float* Wp2 = (const float*)d_in[16];
    const float* bp2 = (const float*)d_in[17];
    float* out = (float*)d_out;

    char* ws = (char*)d_ws;
    size_t off = 0;
    auto alloc = [&](size_t bytes) -> void* {
        void* p = ws + off;
        off = (off + bytes + 255) & ~(size_t)255;
        return p;
    };
    int*   cnt     = (int*)alloc((size_t)NT * 4);     // degcnt[N] ++ gcnt[G]
    int*   row_ptr = (int*)alloc((size_t)(N + 1) * 4);
    int*   cursor  = (int*)alloc((size_t)N * 4);
    float* dinv    = (float*)alloc((size_t)N * 4);
    int*   gstart  = (int*)alloc((size_t)G * 4);
    int*   bsum    = (int*)alloc(2048 * 4);
    int*   boffs   = (int*)alloc(2048 * 4);
    int*   colsS   = (int*)alloc((size_t)E * 4);
    float* hA      = (float*)alloc((size_t)N * 64 * 4);   // M' buffer
    float* hB      = (float*)alloc((size_t)N * 64 * 4);   // h buffer
    float* pooled  = (float*)alloc((size_t)G * 128 * 4);

    int* degcnt = cnt;
    int* gcnt = cnt + N;

    const int nbE = (E + 255) / 256;    // 6250
    const int nbT = (NT + 255) / 256;   // 1627

    hipMemsetAsync(cnt, 0, (size_t)NT * 4, stream);

    k_hist<<<nbE, 256, 0, stream>>>(ei, batch, degcnt, gcnt, E, N);
    k_scan_blocksum<<<nbT, 256, 0, stream>>>(cnt, bsum, NT);
    k_scan_single<<<1, 256, 0, stream>>>(bsum, boffs, nbT);
    k_scan_final<<<nbT, 256, 0, stream>>>(cnt, boffs, row_ptr, cursor, dinv, gstart,
                                          NT, N, E);
    k_scatter<<<nbE, 256, 0, stream>>>(ei, ei + E, cursor, colsS, E);

    // layer 1: M' = Dinv(x@W1);  h1 = relu(di*(M'_i + sum_j M'_j) + b1)
    k_gemm<32><<<2048, 256, 0, stream>>>(x, W1, dinv, hA, N);
    k_agg<<<4096, 256, 0, stream>>>(hA, b1, row_ptr, colsS, dinv, hB, N);
    // layer 2
    k_gemm<64><<<2048, 256, 0, stream>>>(hB, W2, dinv, hA, N);
    k_agg<<<4096, 256, 0, stream>>>(hA, b2, row_ptr, colsS, dinv, hB, N);
    // layer 3
    k_gemm<64><<<2048, 256, 0, stream>>>(hB, W3, dinv, hA, N);
    k_agg<<<4096, 256, 0, stream>>>(hA, b3, row_ptr, colsS, dinv, hB, N);

    k_pool<<<1024, 256, 0, stream>>>(hB, gstart, gcnt, pooled, G);

    k_pred<<<512, 256, 0, stream>>>(pooled, metadata, species, emb, Wm, bm, Wp1, bp1, Wp2,
                                    bp2, out, G);
}

// Round 4
// 948.891 us; speedup vs baseline: 1.4708x; 1.4708x over previous
//
#include <hip/hip_runtime.h>
#include <hip/hip_bf16.h>

#define N_NODES 400000
#define N_EDGES 1600000
#define N_GRAPHS 16384

typedef __attribute__((ext_vector_type(8))) short bf16x8;
typedef __attribute__((ext_vector_type(4))) float f32x4;

__device__ __forceinline__ float rlane(float x, int k) {
    return __int_as_float(__builtin_amdgcn_readlane(__float_as_int(x), k));
}

__device__ __forceinline__ short f2bf(float x) {  // RNE float -> bf16 bits
    unsigned u = __float_as_uint(x);
    unsigned r = (u + 0x7fffu + ((u >> 16) & 1u)) >> 16;
    return (short)r;
}
__device__ __forceinline__ float bf2f(short b) {
    return __uint_as_float(((unsigned)(unsigned short)b) << 16);
}

// ---- fused histogram: edge degree + batch counts ----
__global__ void k_hist(const int* __restrict__ rows, const int* __restrict__ batch,
                       int* __restrict__ degcnt, int* __restrict__ gcnt, int E, int N) {
    int t = blockIdx.x * blockDim.x + threadIdx.x;
    if (t < E) atomicAdd(&degcnt[rows[t]], 1);
    if (t < N) atomicAdd(&gcnt[batch[t]], 1);
}

// ---- scan step 1: per-block sums over concat(degcnt, gcnt) ----
__global__ void k_scan_blocksum(const int* __restrict__ src, int* __restrict__ bsum, int n) {
    __shared__ int s[256];
    int t = threadIdx.x;
    int idx = blockIdx.x * 256 + t;
    int v = idx < n ? src[idx] : 0;
    s[t] = v; __syncthreads();
    for (int off = 128; off > 0; off >>= 1) {
        if (t < off) s[t] += s[t + off];
        __syncthreads();
    }
    if (t == 0) bsum[blockIdx.x] = s[0];
}

// ---- scan step 2: single-block exclusive scan of block sums ----
__global__ void k_scan_single(const int* __restrict__ src, int* __restrict__ dst, int n) {
    __shared__ int s[256];
    __shared__ int carry_s;
    int t = threadIdx.x;
    if (t == 0) carry_s = 0;
    __syncthreads();
    for (int base = 0; base < n; base += 256) {
        int idx = base + t;
        int v = idx < n ? src[idx] : 0;
        s[t] = v; __syncthreads();
        for (int off = 1; off < 256; off <<= 1) {
            int x = (t >= off) ? s[t - off] : 0;
            __syncthreads();
            s[t] += x;
            __syncthreads();
        }
        int incl = s[t];
        int carry = carry_s;
        if (idx < n) dst[idx] = carry + incl - v;
        __syncthreads();
        if (t == 255) carry_s = carry + incl;
        __syncthreads();
    }
}

// ---- scan step 3: final exclusive scan; write row_ptr[N+1]/cursor/dinv/gstart ----
__global__ void k_scan_final(const int* __restrict__ src, const int* __restrict__ boffs,
                             int* __restrict__ row_ptr, int* __restrict__ cursor,
                             float* __restrict__ dinv, int* __restrict__ gstart,
                             int n, int N, int E) {
    __shared__ int s[256];
    int t = threadIdx.x;
    int idx = blockIdx.x * 256 + t;
    int v = idx < n ? src[idx] : 0;
    s[t] = v; __syncthreads();
    for (int off = 1; off < 256; off <<= 1) {
        int x = (t >= off) ? s[t - off] : 0;
        __syncthreads();
        s[t] += x;
        __syncthreads();
    }
    if (idx < n) {
        int excl = boffs[blockIdx.x] + s[t] - v;
        if (idx < N) {
            row_ptr[idx] = excl;
            cursor[idx] = excl;
            dinv[idx] = rsqrtf((float)v + 1.0f);
        } else {
            if (idx == N) row_ptr[N] = E;
            gstart[idx - N] = excl - E;
        }
    }
}

// ---- scatter edge cols into CSR (4B payload; dinv folded into GEMM) ----
__global__ void k_scatter(const int* __restrict__ rows, const int* __restrict__ colsIn,
                          int* __restrict__ cursor, int* __restrict__ colsOut, int E) {
    int e = blockIdx.x * blockDim.x + threadIdx.x;
    if (e < E) {
        int r = rows[e];
        int pos = atomicAdd(&cursor[r], 1);
        colsOut[pos] = colsIn[e];
    }
}

// ---- MFMA GEMM: out[i][c] = dinv[i] * sum_k in[i][k] * W[k][c] ----
// One wave per 16-node tile. Split-bf16 (hi/lo) for ~fp32 precision:
// a*b ~= ahi*bhi + ahi*blo + alo*bhi  (dropped alo*blo ~ 2^-16 rel).
// A-frag: lane holds A[m=lane&15][k=(lane>>4)*8+j]; B-frag: B[k][n=lane&15],
// same k mapping; C/D: col=lane&15, row=(lane>>4)*4+reg.
template <int IN_D>
__global__ __launch_bounds__(256, 2) void k_gemm_mfma(
        const float* __restrict__ in, const float* __restrict__ W,
        const float* __restrict__ dinv, float* __restrict__ out, int N) {
    constexpr int KT = IN_D / 32;  // k-tiles of 32
    const int lane = threadIdx.x & 63;
    const int wave = threadIdx.x >> 6;
    const int m = lane & 15;   // row / col within 16
    const int q = lane >> 4;   // quad

    // Build W hi/lo B-fragments (held in VGPRs; static indexing only).
    bf16x8 Bhi[4][KT], Blo[4][KT];
#pragma unroll
    for (int nt = 0; nt < 4; ++nt) {
#pragma unroll
        for (int kt = 0; kt < KT; ++kt) {
#pragma unroll
            for (int j = 0; j < 8; ++j) {
                int k = kt * 32 + q * 8 + j;
                float w = W[k * 64 + nt * 16 + m];
                short hi = f2bf(w);
                Bhi[nt][kt][j] = hi;
                Blo[nt][kt][j] = f2bf(w - bf2f(hi));
            }
        }
    }

    const int tile = blockIdx.x * 4 + wave;   // 16-node tile id
    const int node0 = tile * 16;
    if (node0 >= N) return;

    const float dv = dinv[node0 + m];
    const float* rowp = in + (size_t)(node0 + m) * IN_D + q * 8;

    bf16x8 Ahi[KT], Alo[KT];
#pragma unroll
    for (int kt = 0; kt < KT; ++kt) {
        f32x4 a0 = *(const f32x4*)(rowp + kt * 32);
        f32x4 a1 = *(const f32x4*)(rowp + kt * 32 + 4);
#pragma unroll
        for (int j = 0; j < 4; ++j) {
            float x = dv * a0[j];
            short hi = f2bf(x);
            Ahi[kt][j] = hi;
            Alo[kt][j] = f2bf(x - bf2f(hi));
        }
#pragma unroll
        for (int j = 0; j < 4; ++j) {
            float x = dv * a1[j];
            short hi = f2bf(x);
            Ahi[kt][4 + j] = hi;
            Alo[kt][4 + j] = f2bf(x - bf2f(hi));
        }
    }

    f32x4 C[4];
#pragma unroll
    for (int nt = 0; nt < 4; ++nt) C[nt] = (f32x4){0.f, 0.f, 0.f, 0.f};

#pragma unroll
    for (int nt = 0; nt < 4; ++nt) {
#pragma unroll
        for (int kt = 0; kt < KT; ++kt) {
            C[nt] = __builtin_amdgcn_mfma_f32_16x16x32_bf16(Ahi[kt], Bhi[nt][kt], C[nt], 0, 0, 0);
            C[nt] = __builtin_amdgcn_mfma_f32_16x16x32_bf16(Ahi[kt], Blo[nt][kt], C[nt], 0, 0, 0);
            C[nt] = __builtin_amdgcn_mfma_f32_16x16x32_bf16(Alo[kt], Bhi[nt][kt], C[nt], 0, 0, 0);
        }
    }

    float* op = out + (size_t)node0 * 64;
#pragma unroll
    for (int nt = 0; nt < 4; ++nt) {
#pragma unroll
        for (int r = 0; r < 4; ++r) {
            int row = q * 4 + r;
            op[(size_t)row * 64 + nt * 16 + m] = C[nt][r];
        }
    }
}

// ---- aggregation: h[i][lane] = relu( di*(M[i] + sum_{j in N(i)} M[j]) + b ) ----
__global__ __launch_bounds__(256, 8) void k_agg(
        const float* __restrict__ M, const float* __restrict__ bias,
        const int* __restrict__ row_ptr, const int* __restrict__ cols,
        const float* __restrict__ dinv, float* __restrict__ out, int N) {
    const int lane = threadIdx.x & 63;
    int wid = (blockIdx.x * blockDim.x + threadIdx.x) >> 6;
    wid = __builtin_amdgcn_readfirstlane(wid);
    const int nw = (gridDim.x * blockDim.x) >> 6;
    const int chunk = (N + nw - 1) / nw;
    const int i0 = wid * chunk;
    const int i1 = min(i0 + chunk, N);
    const float b = bias[lane];

    for (int i = i0; i < i1; ++i) {
        const int s0 = row_ptr[i];
        const int s1 = row_ptr[i + 1];
        const float di = dinv[i];
        float acc = M[(size_t)i * 64 + lane];  // self term
        int e = s0;
        for (; e + 4 <= s1; e += 4) {
            int c0 = cols[e + 0];
            int c1 = cols[e + 1];
            int c2 = cols[e + 2];
            int c3 = cols[e + 3];
            float v0 = M[(size_t)c0 * 64 + lane];
            float v1 = M[(size_t)c1 * 64 + lane];
            float v2 = M[(size_t)c2 * 64 + lane];
            float v3 = M[(size_t)c3 * 64 + lane];
            acc += ((v0 + v1) + (v2 + v3));
        }
        for (; e < s1; ++e) {
            acc += M[(size_t)cols[e] * 64 + lane];
        }
        float h = fmaxf(fmaf(di, acc, b), 0.0f);
        out[(size_t)i * 64 + lane] = h;
    }
}

// ---- pooling: wave per graph, 4 nodes in flight ----
__global__ void k_pool(const float* __restrict__ h, const int* __restrict__ gstart,
                       const int* __restrict__ gcnt, float* __restrict__ pooled, int G) {
    const int lane = threadIdx.x & 63;
    const int c = lane & 15;
    const int g = lane >> 4;
    const int wid = (blockIdx.x * blockDim.x + threadIdx.x) >> 6;
    const int nw = (gridDim.x * blockDim.x) >> 6;
    const float NEG = -3.402823466e38f;
    for (int gr = wid; gr < G; gr += nw) {
        int gs = gstart[gr], gc = gcnt[gr];
        float4 sum = {0.f, 0.f, 0.f, 0.f};
        float4 mx = {NEG, NEG, NEG, NEG};
        const float* base = h + (size_t)gs * 64 + 4 * c;
        for (int p = g; p < gc; p += 4) {
            float4 v = *(const float4*)(base + (size_t)p * 64);
            sum.x += v.x; sum.y += v.y; sum.z += v.z; sum.w += v.w;
            mx.x = fmaxf(mx.x, v.x); mx.y = fmaxf(mx.y, v.y);
            mx.z = fmaxf(mx.z, v.z); mx.w = fmaxf(mx.w, v.w);
        }
#pragma unroll
        for (int s = 16; s < 64; s <<= 1) {
            sum.x += __shfl_xor(sum.x, s); sum.y += __shfl_xor(sum.y, s);
            sum.z += __shfl_xor(sum.z, s); sum.w += __shfl_xor(sum.w, s);
            mx.x = fmaxf(mx.x, __shfl_xor(mx.x, s));
            mx.y = fmaxf(mx.y, __shfl_xor(mx.y, s));
            mx.z = fmaxf(mx.z, __shfl_xor(mx.z, s));
            mx.w = fmaxf(mx.w, __shfl_xor(mx.w, s));
        }
        float inv = 1.0f / fmaxf((float)gc, 1.0f);
        float4 mean = {sum.x * inv, sum.y * inv, sum.z * inv, sum.w * inv};
        float4 mxo = gc > 0 ? mx : make_float4(0.f, 0.f, 0.f, 0.f);
        if (lane < 16) {
            *(float4*)(pooled + (size_t)gr * 128 + 4 * c) = mean;
            *(float4*)(pooled + (size_t)gr * 128 + 64 + 4 * c) = mxo;
        }
    }
}

// ---- predictor: fused meta-encoder + MLP head; one wave per graph ----
__global__ void k_pred(const float* __restrict__ pooled, const float* __restrict__ metadata,
                       const int* __restrict__ species, const float* __restrict__ emb,
                       const float* __restrict__ Wm, const float* __restrict__ bm,
                       const float* __restrict__ Wp1, const float* __restrict__ bp1,
                       const float* __restrict__ Wp2, const float* __restrict__ bp2,
                       float* __restrict__ out, int G) {
    __shared__ float Wp1L[208 * 64];
    __shared__ float WmL[16 * 64];
    __shared__ float bp1L[64], bmL[64], Wp2L[64];
    int t = threadIdx.x;
    for (int idx = t; idx < 208 * 64; idx += blockDim.x) Wp1L[idx] = Wp1[idx];
    for (int idx = t; idx < 16 * 64; idx += blockDim.x) WmL[idx] = Wm[idx];
    if (t < 64) {
        bp1L[t] = bp1[t];
        bmL[t] = bm[t];
        Wp2L[t] = Wp2[t];
    }
    __syncthreads();
    const float bp2v = bp2[0];
    const int lane = t & 63;
    const int wid = (blockIdx.x * blockDim.x + t) >> 6;
    const int nw = (gridDim.x * blockDim.x) >> 6;
    for (int g = wid; g < G; g += nw) {
        float f0 = pooled[g * 128 + lane];        // mean
        float f1 = pooled[g * 128 + 64 + lane];   // max
        float md = lane < 16 ? metadata[g * 16 + lane] : 0.0f;
        float m = bmL[lane];
#pragma unroll
        for (int k = 0; k < 16; ++k) m = fmaf(rlane(md, k), WmL[k * 64 + lane], m);
        float f2 = fmaxf(m, 0.0f);                // meta relu
        int sid = species[g];
        float f3 = lane < 16 ? emb[sid * 16 + lane] : 0.0f;  // species emb
        float tacc = bp1L[lane];
#pragma unroll
        for (int k = 0; k < 64; ++k) tacc = fmaf(rlane(f0, k), Wp1L[k * 64 + lane], tacc);
#pragma unroll
        for (int k = 0; k < 64; ++k) tacc = fmaf(rlane(f1, k), Wp1L[(64 + k) * 64 + lane], tacc);
#pragma unroll
        for (int k = 0; k < 64; ++k) tacc = fmaf(rlane(f2, k), Wp1L[(128 + k) * 64 + lane], tacc);
#pragma unroll
        for (int k = 0; k < 16; ++k) tacc = fmaf(rlane(f3, k), Wp1L[(192 + k) * 64 + lane], tacc);
        tacc = fmaxf(tacc, 0.0f);
        float r = tacc * Wp2L[lane];
        for (int off = 32; off > 0; off >>= 1) r += __shfl_down(r, off);
        if (lane == 0) out[g] = r + bp2v;
    }
}

extern "C" void kernel_launch(void* const* d_in, const int* in_sizes, int n_in,
                              void* d_out, int out_size, void* d_ws, size_t ws_size,
                              hipStream_t stream) {
    const int N = N_NODES, E = N_EDGES, G = N_GRAPHS;
    const int NT = N + G;

    const float* x        = (const float*)d_in[0];
    const float* metadata = (const float*)d_in[1];
    const int*   ei       = (const int*)d_in[2];
    const int*   batch    = (const int*)d_in[3];
    const int*   species  = (const int*)d_in[4];
    const float* W1 = (const float*)d_in[5];
    const float* b1 = (const float*)d_in[6];
    const float* W2 = (const float*)d_in[7];
    const float* b2 = (const float*)d_in[8];
    const float* W3 = (const float*)d_in[9];
    const float* b3 = (const float*)d_in[10];
    const float* Wm = (const float*)d_in[11];
    const float* bm = (const float*)d_in[12];
    const float* emb = (const float*)d_in[13];
    const float* Wp1 = (const float*)d_in[14];
    const float* bp1 = (const float*)d_in[15];
    const float* Wp2 = (const float*)d_in[16];
    const float* bp2 = (const float*)d_in[17];
    float* out = (float*)d_out;

    char* ws = (char*)d_ws;
    size_t off = 0;
    auto alloc = [&](size_t bytes) -> void* {
        void* p = ws + off;
        off = (off + bytes + 255) & ~(size_t)255;
        return p;
    };
    int*   cnt     = (int*)alloc((size_t)NT * 4);
    int*   row_ptr = (int*)alloc((size_t)(N + 1) * 4);
    int*   cursor  = (int*)alloc((size_t)N * 4);
    float* dinv    = (float*)alloc((size_t)N * 4);
    int*   gstart  = (int*)alloc((size_t)G * 4);
    int*   bsum    = (int*)alloc(2048 * 4);
    int*   boffs   = (int*)alloc(2048 * 4);
    int*   colsS   = (int*)alloc((size_t)E * 4);
    float* hA      = (float*)alloc((size_t)N * 64 * 4);   // M' buffer
    float* hB      = (float*)alloc((size_t)N * 64 * 4);   // h buffer
    float* pooled  = (float*)alloc((size_t)G * 128 * 4);

    int* degcnt = cnt;
    int* gcnt = cnt + N;

    const int nbE = (E + 255) / 256;    // 6250
    const int nbT = (NT + 255) / 256;   // 1627
    const int nbG = (N / 16 + 3) / 4;   // 6250 blocks, 4 tiles each

    hipMemsetAsync(cnt, 0, (size_t)NT * 4, stream);

    k_hist<<<nbE, 256, 0, stream>>>(ei, batch, degcnt, gcnt, E, N);
    k_scan_blocksum<<<nbT, 256, 0, stream>>>(cnt, bsum, NT);
    k_scan_single<<<1, 256, 0, stream>>>(bsum, boffs, nbT);
    k_scan_final<<<nbT, 256, 0, stream>>>(cnt, boffs, row_ptr, cursor, dinv, gstart,
                                          NT, N, E);
    k_scatter<<<nbE, 256, 0, stream>>>(ei, ei + E, cursor, colsS, E);

    // layer 1: M' = Dinv(x@W1);  h1 = relu(di*(M'_i + sum_j M'_j) + b1)
    k_gemm_mfma<32><<<nbG, 256, 0, stream>>>(x, W1, dinv, hA, N);
    k_agg<<<4096, 256, 0, stream>>>(hA, b1, row_ptr, colsS, dinv, hB, N);
    // layer 2
    k_gemm_mfma<64><<<nbG, 256, 0, stream>>>(hB, W2, dinv, hA, N);
    k_agg<<<4096, 256, 0, stream>>>(hA, b2, row_ptr, colsS, dinv, hB, N);
    // layer 3
    k_gemm_mfma<64><<<nbG, 256, 0, stream>>>(hB, W3, dinv, hA, N);
    k_agg<<<4096, 256, 0, stream>>>(hA, b3, row_ptr, colsS, dinv, hB, N);

    k_pool<<<1024, 256, 0, stream>>>(hB, gstart, gcnt, pooled, G);

    k_pred<<<512, 256, 0, stream>>>(pooled, metadata, species, emb, Wm, bm, Wp1, bp1, Wp2,
                                    bp2, out, G);
}

// Round 5
// 741.316 us; speedup vs baseline: 1.8826x; 1.2800x over previous
//
#include <hip/hip_runtime.h>
#include <hip/hip_bf16.h>

#define N_NODES 400000
#define N_EDGES 1600000
#define N_GRAPHS 16384

typedef __attribute__((ext_vector_type(8))) short bf16x8;
typedef __attribute__((ext_vector_type(4))) float f32x4;

__device__ __forceinline__ float rlane(float x, int k) {
    return __int_as_float(__builtin_amdgcn_readlane(__float_as_int(x), k));
}

__device__ __forceinline__ short f2bf(float x) {  // RNE float -> bf16 bits
    unsigned u = __float_as_uint(x);
    unsigned r = (u + 0x7fffu + ((u >> 16) & 1u)) >> 16;
    return (short)r;
}
__device__ __forceinline__ float bf2f(short b) {
    return __uint_as_float(((unsigned)(unsigned short)b) << 16);
}

// ---- fused histogram: edge degree + batch counts ----
__global__ void k_hist(const int* __restrict__ rows, const int* __restrict__ batch,
                       int* __restrict__ degcnt, int* __restrict__ gcnt, int E, int N) {
    int t = blockIdx.x * blockDim.x + threadIdx.x;
    if (t < E) atomicAdd(&degcnt[rows[t]], 1);
    if (t < N) atomicAdd(&gcnt[batch[t]], 1);
}

// ---- scan step 1: per-block sums over concat(degcnt, gcnt) ----
__global__ void k_scan_blocksum(const int* __restrict__ src, int* __restrict__ bsum, int n) {
    __shared__ int s[256];
    int t = threadIdx.x;
    int idx = blockIdx.x * 256 + t;
    int v = idx < n ? src[idx] : 0;
    s[t] = v; __syncthreads();
    for (int off = 128; off > 0; off >>= 1) {
        if (t < off) s[t] += s[t + off];
        __syncthreads();
    }
    if (t == 0) bsum[blockIdx.x] = s[0];
}

// ---- scan step 2: single-block exclusive scan of block sums ----
__global__ void k_scan_single(const int* __restrict__ src, int* __restrict__ dst, int n) {
    __shared__ int s[256];
    __shared__ int carry_s;
    int t = threadIdx.x;
    if (t == 0) carry_s = 0;
    __syncthreads();
    for (int base = 0; base < n; base += 256) {
        int idx = base + t;
        int v = idx < n ? src[idx] : 0;
        s[t] = v; __syncthreads();
        for (int off = 1; off < 256; off <<= 1) {
            int x = (t >= off) ? s[t - off] : 0;
            __syncthreads();
            s[t] += x;
            __syncthreads();
        }
        int incl = s[t];
        int carry = carry_s;
        if (idx < n) dst[idx] = carry + incl - v;
        __syncthreads();
        if (t == 255) carry_s = carry + incl;
        __syncthreads();
    }
}

// ---- scan step 3: final exclusive scan; write row_ptr[N+1]/cursor/dinv/gstart ----
__global__ void k_scan_final(const int* __restrict__ src, const int* __restrict__ boffs,
                             int* __restrict__ row_ptr, int* __restrict__ cursor,
                             float* __restrict__ dinv, int* __restrict__ gstart,
                             int n, int N, int E) {
    __shared__ int s[256];
    int t = threadIdx.x;
    int idx = blockIdx.x * 256 + t;
    int v = idx < n ? src[idx] : 0;
    s[t] = v; __syncthreads();
    for (int off = 1; off < 256; off <<= 1) {
        int x = (t >= off) ? s[t - off] : 0;
        __syncthreads();
        s[t] += x;
        __syncthreads();
    }
    if (idx < n) {
        int excl = boffs[blockIdx.x] + s[t] - v;
        if (idx < N) {
            row_ptr[idx] = excl;
            cursor[idx] = excl;
            dinv[idx] = rsqrtf((float)v + 1.0f);
        } else {
            if (idx == N) row_ptr[N] = E;
            gstart[idx - N] = excl - E;
        }
    }
}

// ---- scatter edge cols into CSR (4B payload; dinv folded into GEMM) ----
__global__ void k_scatter(const int* __restrict__ rows, const int* __restrict__ colsIn,
                          int* __restrict__ cursor, int* __restrict__ colsOut, int E) {
    int e = blockIdx.x * blockDim.x + threadIdx.x;
    if (e < E) {
        int r = rows[e];
        int pos = atomicAdd(&cursor[r], 1);
        colsOut[pos] = colsIn[e];
    }
}

// ---- MFMA GEMM: out[i][c] = dinv[i] * sum_k in[i][k] * W[k][c] ----
// Split-bf16 (hi/lo): a*b ~= ahi*bhi + ahi*blo + alo*bhi.
template <int IN_D>
__global__ __launch_bounds__(256, 2) void k_gemm_mfma(
        const float* __restrict__ in, const float* __restrict__ W,
        const float* __restrict__ dinv, float* __restrict__ out, int N) {
    constexpr int KT = IN_D / 32;  // k-tiles of 32
    const int lane = threadIdx.x & 63;
    const int wave = threadIdx.x >> 6;
    const int m = lane & 15;   // row / col within 16
    const int q = lane >> 4;   // quad

    bf16x8 Bhi[4][KT], Blo[4][KT];
#pragma unroll
    for (int nt = 0; nt < 4; ++nt) {
#pragma unroll
        for (int kt = 0; kt < KT; ++kt) {
#pragma unroll
            for (int j = 0; j < 8; ++j) {
                int k = kt * 32 + q * 8 + j;
                float w = W[k * 64 + nt * 16 + m];
                short hi = f2bf(w);
                Bhi[nt][kt][j] = hi;
                Blo[nt][kt][j] = f2bf(w - bf2f(hi));
            }
        }
    }

    const int tile = blockIdx.x * 4 + wave;
    const int node0 = tile * 16;
    if (node0 >= N) return;

    const float dv = dinv[node0 + m];
    const float* rowp = in + (size_t)(node0 + m) * IN_D + q * 8;

    bf16x8 Ahi[KT], Alo[KT];
#pragma unroll
    for (int kt = 0; kt < KT; ++kt) {
        f32x4 a0 = *(const f32x4*)(rowp + kt * 32);
        f32x4 a1 = *(const f32x4*)(rowp + kt * 32 + 4);
#pragma unroll
        for (int j = 0; j < 4; ++j) {
            float x = dv * a0[j];
            short hi = f2bf(x);
            Ahi[kt][j] = hi;
            Alo[kt][j] = f2bf(x - bf2f(hi));
        }
#pragma unroll
        for (int j = 0; j < 4; ++j) {
            float x = dv * a1[j];
            short hi = f2bf(x);
            Ahi[kt][4 + j] = hi;
            Alo[kt][4 + j] = f2bf(x - bf2f(hi));
        }
    }

    f32x4 C[4];
#pragma unroll
    for (int nt = 0; nt < 4; ++nt) C[nt] = (f32x4){0.f, 0.f, 0.f, 0.f};

#pragma unroll
    for (int nt = 0; nt < 4; ++nt) {
#pragma unroll
        for (int kt = 0; kt < KT; ++kt) {
            C[nt] = __builtin_amdgcn_mfma_f32_16x16x32_bf16(Ahi[kt], Bhi[nt][kt], C[nt], 0, 0, 0);
            C[nt] = __builtin_amdgcn_mfma_f32_16x16x32_bf16(Ahi[kt], Blo[nt][kt], C[nt], 0, 0, 0);
            C[nt] = __builtin_amdgcn_mfma_f32_16x16x32_bf16(Alo[kt], Bhi[nt][kt], C[nt], 0, 0, 0);
        }
    }

    float* op = out + (size_t)node0 * 64;
#pragma unroll
    for (int nt = 0; nt < 4; ++nt) {
#pragma unroll
        for (int r = 0; r < 4; ++r) {
            int row = q * 4 + r;
            op[(size_t)row * 64 + nt * 16 + m] = C[nt][r];
        }
    }
}

// ---- aggregation (layers 1-2): h[i] = relu( di*(M[i] + sum_j M[j]) + b ) ----
__global__ __launch_bounds__(256, 8) void k_agg(
        const float* __restrict__ M, const float* __restrict__ bias,
        const int* __restrict__ row_ptr, const int* __restrict__ cols,
        const float* __restrict__ dinv, float* __restrict__ out, int N) {
    const int lane = threadIdx.x & 63;
    int wid = (blockIdx.x * blockDim.x + threadIdx.x) >> 6;
    wid = __builtin_amdgcn_readfirstlane(wid);
    const int nw = (gridDim.x * blockDim.x) >> 6;
    const int chunk = (N + nw - 1) / nw;
    const int i0 = wid * chunk;
    const int i1 = min(i0 + chunk, N);
    const float b = bias[lane];

    for (int i = i0; i < i1; ++i) {
        const int s0 = row_ptr[i];
        const int s1 = row_ptr[i + 1];
        const float di = dinv[i];
        float acc = M[(size_t)i * 64 + lane];
        int e = s0;
        for (; e + 4 <= s1; e += 4) {
            int c0 = cols[e + 0];
            int c1 = cols[e + 1];
            int c2 = cols[e + 2];
            int c3 = cols[e + 3];
            float v0 = M[(size_t)c0 * 64 + lane];
            float v1 = M[(size_t)c1 * 64 + lane];
            float v2 = M[(size_t)c2 * 64 + lane];
            float v3 = M[(size_t)c3 * 64 + lane];
            acc += ((v0 + v1) + (v2 + v3));
        }
        for (; e < s1; ++e) {
            acc += M[(size_t)cols[e] * 64 + lane];
        }
        float h = fmaxf(fmaf(di, acc, b), 0.0f);
        out[(size_t)i * 64 + lane] = h;
    }
}

// ---- fused layer-3 agg + mean/max pool + meta encoder + fused assembly ----
// One wave per graph (batch sorted -> contiguous node range). Writes
// fused[g][0:224] = [mean(64) | max(64) | relu(meta@Wm+bm)(64) | emb(16) | 0(16)]
__global__ __launch_bounds__(256, 8) void k_agg_pool(
        const float* __restrict__ M, const float* __restrict__ b3,
        const int* __restrict__ row_ptr, const int* __restrict__ cols,
        const float* __restrict__ dinv,
        const int* __restrict__ gstart, const int* __restrict__ gcnt,
        const float* __restrict__ metadata, const int* __restrict__ species,
        const float* __restrict__ emb, const float* __restrict__ Wm,
        const float* __restrict__ bm, float* __restrict__ fused, int G) {
    const int lane = threadIdx.x & 63;
    int wv = (blockIdx.x * blockDim.x + threadIdx.x) >> 6;
    wv = __builtin_amdgcn_readfirstlane(wv);
    const int nw = (gridDim.x * blockDim.x) >> 6;
    const float b = b3[lane];
    const float bmr = bm[lane];
    float wmr[16];
#pragma unroll
    for (int k = 0; k < 16; ++k) wmr[k] = Wm[k * 64 + lane];

    for (int g = wv; g < G; g += nw) {
        const int gs = gstart[g];
        const int gc = gcnt[g];
        float sum = 0.0f;
        float mx = -3.402823466e38f;
        for (int i = gs; i < gs + gc; ++i) {
            const int s0 = row_ptr[i];
            const int s1 = row_ptr[i + 1];
            const float di = dinv[i];
            float acc = M[(size_t)i * 64 + lane];
            int e = s0;
            for (; e + 4 <= s1; e += 4) {
                int c0 = cols[e + 0];
                int c1 = cols[e + 1];
                int c2 = cols[e + 2];
                int c3 = cols[e + 3];
                float v0 = M[(size_t)c0 * 64 + lane];
                float v1 = M[(size_t)c1 * 64 + lane];
                float v2 = M[(size_t)c2 * 64 + lane];
                float v3 = M[(size_t)c3 * 64 + lane];
                acc += ((v0 + v1) + (v2 + v3));
            }
            for (; e < s1; ++e) acc += M[(size_t)cols[e] * 64 + lane];
            float h = fmaxf(fmaf(di, acc, b), 0.0f);
            sum += h;
            mx = fmaxf(mx, h);
        }
        float mean = sum / fmaxf((float)gc, 1.0f);
        if (gc == 0) mx = 0.0f;
        // meta encoder
        float md = lane < 16 ? metadata[(size_t)g * 16 + lane] : 0.0f;
        float mval = bmr;
#pragma unroll
        for (int k = 0; k < 16; ++k) mval = fmaf(rlane(md, k), wmr[k], mval);
        mval = fmaxf(mval, 0.0f);
        const int sid = species[g];
        float* fr = fused + (size_t)g * 224;
        fr[lane] = mean;
        fr[64 + lane] = mx;
        fr[128 + lane] = mval;
        if (lane < 16) fr[192 + lane] = emb[(size_t)sid * 16 + lane];
        else if (lane < 32) fr[192 + lane] = 0.0f;   // zero pad cols 208..223
    }
}

// ---- MFMA predictor head: out = relu(fused @ Wp1 + bp1) @ Wp2 + bp2 ----
// Wp1 staged once per block into LDS as transposed hi/lo bf16 (rows padded to
// 232 shorts for conflict-free ds_read_b128). 16 graphs per wave.
__global__ __launch_bounds__(256, 2) void k_pred_mfma(
        const float* __restrict__ fused, const float* __restrict__ Wp1,
        const float* __restrict__ bp1, const float* __restrict__ Wp2,
        const float* __restrict__ bp2, float* __restrict__ out, int G) {
    __shared__ __align__(16) short Whi[64 * 232];
    __shared__ __align__(16) short Wlo[64 * 232];
    const int t = threadIdx.x;
    for (int idx = t; idx < 64 * 232; idx += 256) {
        int n = idx / 232;
        int k = idx % 232;
        float w = (k < 208) ? Wp1[(size_t)k * 64 + n] : 0.0f;
        short hi = f2bf(w);
        Whi[n * 232 + k] = hi;
        Wlo[n * 232 + k] = f2bf(w - bf2f(hi));
    }
    __syncthreads();

    const int lane = t & 63;
    const int wave = t >> 6;
    const int m = lane & 15;
    const int q = lane >> 4;
    const int g0 = (blockIdx.x * 4 + wave) * 16;
    if (g0 >= G) return;

    const float* rowp = fused + (size_t)(g0 + m) * 224 + q * 8;

    f32x4 C[4];
#pragma unroll
    for (int nt = 0; nt < 4; ++nt) C[nt] = (f32x4){0.f, 0.f, 0.f, 0.f};

#pragma unroll
    for (int kt = 0; kt < 7; ++kt) {
        f32x4 a0 = *(const f32x4*)(rowp + kt * 32);
        f32x4 a1 = *(const f32x4*)(rowp + kt * 32 + 4);
        bf16x8 Ahi, Alo;
#pragma unroll
        for (int j = 0; j < 4; ++j) {
            short hi = f2bf(a0[j]);
            Ahi[j] = hi;
            Alo[j] = f2bf(a0[j] - bf2f(hi));
        }
#pragma unroll
        for (int j = 0; j < 4; ++j) {
            short hi = f2bf(a1[j]);
            Ahi[4 + j] = hi;
            Alo[4 + j] = f2bf(a1[j] - bf2f(hi));
        }
#pragma unroll
        for (int nt = 0; nt < 4; ++nt) {
            const int boff = (nt * 16 + m) * 232 + kt * 32 + q * 8;
            bf16x8 Bh = *(const bf16x8*)&Whi[boff];
            bf16x8 Bl = *(const bf16x8*)&Wlo[boff];
            C[nt] = __builtin_amdgcn_mfma_f32_16x16x32_bf16(Ahi, Bh, C[nt], 0, 0, 0);
            C[nt] = __builtin_amdgcn_mfma_f32_16x16x32_bf16(Ahi, Bl, C[nt], 0, 0, 0);
            C[nt] = __builtin_amdgcn_mfma_f32_16x16x32_bf16(Alo, Bh, C[nt], 0, 0, 0);
        }
    }

    // epilogue: s[r] = sum_cols relu(C + bp1) * Wp2; reduce over m within quad
    float wp2r[4], bp1r[4];
#pragma unroll
    for (int nt = 0; nt < 4; ++nt) {
        wp2r[nt] = Wp2[nt * 16 + m];
        bp1r[nt] = bp1[nt * 16 + m];
    }
    const float bp2v = bp2[0];
    float s[4];
#pragma unroll
    for (int r = 0; r < 4; ++r) {
        float acc = 0.0f;
#pragma unroll
        for (int nt = 0; nt < 4; ++nt)
            acc += fmaxf(C[nt][r] + bp1r[nt], 0.0f) * wp2r[nt];
        s[r] = acc;
    }
#pragma unroll
    for (int off = 1; off < 16; off <<= 1) {
#pragma unroll
        for (int r = 0; r < 4; ++r) s[r] += __shfl_xor(s[r], off);
    }
    if (m == 0) {
#pragma unroll
        for (int r = 0; r < 4; ++r) out[g0 + q * 4 + r] = s[r] + bp2v;
    }
}

extern "C" void kernel_launch(void* const* d_in, const int* in_sizes, int n_in,
                              void* d_out, int out_size, void* d_ws, size_t ws_size,
                              hipStream_t stream) {
    const int N = N_NODES, E = N_EDGES, G = N_GRAPHS;
    const int NT = N + G;

    const float* x        = (const float*)d_in[0];
    const float* metadata = (const float*)d_in[1];
    const int*   ei       = (const int*)d_in[2];
    const int*   batch    = (const int*)d_in[3];
    const int*   species  = (const int*)d_in[4];
    const float* W1 = (const float*)d_in[5];
    const float* b1 = (const float*)d_in[6];
    const float* W2 = (const float*)d_in[7];
    const float* b2 = (const float*)d_in[8];
    const float* W3 = (const float*)d_in[9];
    const float* b3 = (const float*)d_in[10];
    const float* Wm = (const float*)d_in[11];
    const float* bm = (const float*)d_in[12];
    const float* emb = (const float*)d_in[13];
    const float* Wp1 = (const float*)d_in[14];
    const float* bp1 = (const float*)d_in[15];
    const float* Wp2 = (const float*)d_in[16];
    const float* bp2 = (const float*)d_in[17];
    float* out = (float*)d_out;

    char* ws = (char*)d_ws;
    size_t off = 0;
    auto alloc = [&](size_t bytes) -> void* {
        void* p = ws + off;
        off = (off + bytes + 255) & ~(size_t)255;
        return p;
    };
    int*   cnt     = (int*)alloc((size_t)NT * 4);
    int*   row_ptr = (int*)alloc((size_t)(N + 1) * 4);
    int*   cursor  = (int*)alloc((size_t)N * 4);
    float* dinv    = (float*)alloc((size_t)N * 4);
    int*   gstart  = (int*)alloc((size_t)G * 4);
    int*   bsum    = (int*)alloc(2048 * 4);
    int*   boffs   = (int*)alloc(2048 * 4);
    int*   colsS   = (int*)alloc((size_t)E * 4);
    float* hA      = (float*)alloc((size_t)N * 64 * 4);
    float* hB      = (float*)alloc((size_t)N * 64 * 4);
    float* fused   = (float*)alloc((size_t)G * 224 * 4);

    int* degcnt = cnt;
    int* gcnt = cnt + N;

    const int nbE = (E + 255) / 256;    // 6250
    const int nbT = (NT + 255) / 256;   // 1627
    const int nbG = (N / 16 + 3) / 4;   // 6250 blocks, 4 tiles each

    hipMemsetAsync(cnt, 0, (size_t)NT * 4, stream);

    k_hist<<<nbE, 256, 0, stream>>>(ei, batch, degcnt, gcnt, E, N);
    k_scan_blocksum<<<nbT, 256, 0, stream>>>(cnt, bsum, NT);
    k_scan_single<<<1, 256, 0, stream>>>(bsum, boffs, nbT);
    k_scan_final<<<nbT, 256, 0, stream>>>(cnt, boffs, row_ptr, cursor, dinv, gstart,
                                          NT, N, E);
    k_scatter<<<nbE, 256, 0, stream>>>(ei, ei + E, cursor, colsS, E);

    // layer 1
    k_gemm_mfma<32><<<nbG, 256, 0, stream>>>(x, W1, dinv, hA, N);
    k_agg<<<4096, 256, 0, stream>>>(hA, b1, row_ptr, colsS, dinv, hB, N);
    // layer 2
    k_gemm_mfma<64><<<nbG, 256, 0, stream>>>(hB, W2, dinv, hA, N);
    k_agg<<<4096, 256, 0, stream>>>(hA, b2, row_ptr, colsS, dinv, hB, N);
    // layer 3 GEMM, then fused agg+pool+meta+assembly
    k_gemm_mfma<64><<<nbG, 256, 0, stream>>>(hB, W3, dinv, hA, N);
    k_agg_pool<<<2048, 256, 0, stream>>>(hA, b3, row_ptr, colsS, dinv, gstart, gcnt,
                                         metadata, species, emb, Wm, bm, fused, G);

    // predictor head (MFMA)
    k_pred_mfma<<<(G / 16 + 3) / 4, 256, 0, stream>>>(fused, Wp1, bp1, Wp2, bp2, out, G);
}

// Round 6
// 708.201 us; speedup vs baseline: 1.9707x; 1.0468x over previous
//
#include <hip/hip_runtime.h>
#include <hip/hip_bf16.h>

#define N_NODES 400000
#define N_EDGES 1600000
#define N_GRAPHS 16384

#define BSHIFT 11
#define NBKT ((N_NODES + (1 << BSHIFT) - 1) >> BSHIFT)   // 196 row-buckets
#define BIN_CHUNK 4096

typedef __attribute__((ext_vector_type(8))) short bf16x8;
typedef __attribute__((ext_vector_type(4))) float f32x4;

__device__ __forceinline__ float rlane(float x, int k) {
    return __int_as_float(__builtin_amdgcn_readlane(__float_as_int(x), k));
}

__device__ __forceinline__ short f2bf(float x) {  // RNE float -> bf16 bits
    unsigned u = __float_as_uint(x);
    unsigned r = (u + 0x7fffu + ((u >> 16) & 1u)) >> 16;
    return (short)r;
}
__device__ __forceinline__ float bf2f(short b) {
    return __uint_as_float(((unsigned)(unsigned short)b) << 16);
}

// ---- fused histogram: edge degree + batch counts ----
__global__ void k_hist(const int* __restrict__ rows, const int* __restrict__ batch,
                       int* __restrict__ degcnt, int* __restrict__ gcnt, int E, int N) {
    int t = blockIdx.x * blockDim.x + threadIdx.x;
    if (t < E) atomicAdd(&degcnt[rows[t]], 1);
    if (t < N) atomicAdd(&gcnt[batch[t]], 1);
}

// ---- scan step 1: per-block sums over concat(degcnt, gcnt) ----
__global__ void k_scan_blocksum(const int* __restrict__ src, int* __restrict__ bsum, int n) {
    __shared__ int s[256];
    int t = threadIdx.x;
    int idx = blockIdx.x * 256 + t;
    int v = idx < n ? src[idx] : 0;
    s[t] = v; __syncthreads();
    for (int off = 128; off > 0; off >>= 1) {
        if (t < off) s[t] += s[t + off];
        __syncthreads();
    }
    if (t == 0) bsum[blockIdx.x] = s[0];
}

// ---- scan step 2: single-block exclusive scan of block sums ----
__global__ void k_scan_single(const int* __restrict__ src, int* __restrict__ dst, int n) {
    __shared__ int s[256];
    __shared__ int carry_s;
    int t = threadIdx.x;
    if (t == 0) carry_s = 0;
    __syncthreads();
    for (int base = 0; base < n; base += 256) {
        int idx = base + t;
        int v = idx < n ? src[idx] : 0;
        s[t] = v; __syncthreads();
        for (int off = 1; off < 256; off <<= 1) {
            int x = (t >= off) ? s[t - off] : 0;
            __syncthreads();
            s[t] += x;
            __syncthreads();
        }
        int incl = s[t];
        int carry = carry_s;
        if (idx < n) dst[idx] = carry + incl - v;
        __syncthreads();
        if (t == 255) carry_s = carry + incl;
        __syncthreads();
    }
}

// ---- scan step 3: final exclusive scan; row_ptr[N+1]/cursor/dinv/gstart/bcur ----
__global__ void k_scan_final(const int* __restrict__ src, const int* __restrict__ boffs,
                             int* __restrict__ row_ptr, int* __restrict__ cursor,
                             float* __restrict__ dinv, int* __restrict__ gstart,
                             int* __restrict__ bcur, int n, int N, int E) {
    __shared__ int s[256];
    int t = threadIdx.x;
    int idx = blockIdx.x * 256 + t;
    int v = idx < n ? src[idx] : 0;
    s[t] = v; __syncthreads();
    for (int off = 1; off < 256; off <<= 1) {
        int x = (t >= off) ? s[t - off] : 0;
        __syncthreads();
        s[t] += x;
        __syncthreads();
    }
    if (idx < n) {
        int excl = boffs[blockIdx.x] + s[t] - v;
        if (idx < N) {
            row_ptr[idx] = excl;
            cursor[idx] = excl;
            dinv[idx] = rsqrtf((float)v + 1.0f);
            if ((idx & ((1 << BSHIFT) - 1)) == 0) bcur[idx >> BSHIFT] = excl;
        } else {
            if (idx == N) row_ptr[N] = E;
            gstart[idx - N] = excl - E;
        }
    }
}

// ---- scatter phase A: bin edges by row-bucket with LDS-combined writes ----
__global__ __launch_bounds__(256) void k_bin(const int* __restrict__ rows,
                                             const int* __restrict__ cols,
                                             int* __restrict__ bcur,
                                             int2* __restrict__ tmp, int E) {
    __shared__ int lcnt[NBKT];
    __shared__ int lbase[NBKT];
    const int t = threadIdx.x;
    const int e0 = blockIdx.x * BIN_CHUNK;
    for (int i = t; i < NBKT; i += 256) lcnt[i] = 0;
    __syncthreads();
    int r[16];
#pragma unroll
    for (int k = 0; k < 16; ++k) {
        int e = e0 + k * 256 + t;
        r[k] = (e < E) ? rows[e] : -1;
        if (r[k] >= 0) atomicAdd(&lcnt[r[k] >> BSHIFT], 1);
    }
    __syncthreads();
    for (int i = t; i < NBKT; i += 256) lbase[i] = atomicAdd(&bcur[i], lcnt[i]);
    __syncthreads();
    for (int i = t; i < NBKT; i += 256) lcnt[i] = 0;
    __syncthreads();
#pragma unroll
    for (int k = 0; k < 16; ++k) {
        int e = e0 + k * 256 + t;
        if (r[k] >= 0) {
            int b = r[k] >> BSHIFT;
            int p = lbase[b] + atomicAdd(&lcnt[b], 1);
            tmp[p] = make_int2(r[k], cols[e]);
        }
    }
}

// ---- scatter phase B: one block per bucket; writes confined to ~32KB window ----
__global__ __launch_bounds__(256) void k_scat2(const int2* __restrict__ tmp,
                                               const int* __restrict__ row_ptr,
                                               int* __restrict__ cursor,
                                               int* __restrict__ colsOut, int N) {
    const int b = blockIdx.x;
    const int s = row_ptr[b << BSHIFT];
    const int endr = min((b + 1) << BSHIFT, N);
    const int tend = row_ptr[endr];
#pragma unroll 4
    for (int e = s + threadIdx.x; e < tend; e += 256) {
        int2 rc = tmp[e];
        int pos = atomicAdd(&cursor[rc.x], 1);
        colsOut[pos] = rc.y;
    }
}

// ---- layer-1 pre-aggregation on raw x (32ch): xa = Dinv(A+I)Dinv x ----
// Wave handles 2 nodes (half-wave each, 32 channels = 128B rows).
__global__ __launch_bounds__(256, 8) void k_agg32(
        const float* __restrict__ x, const int* __restrict__ row_ptr,
        const int* __restrict__ cols, const float* __restrict__ dinv,
        float* __restrict__ out, int N) {
    const int lane = threadIdx.x & 63;
    const int c = lane & 31;
    const int half = lane >> 5;
    int wid = (blockIdx.x * blockDim.x + threadIdx.x) >> 6;
    wid = __builtin_amdgcn_readfirstlane(wid);
    const int nw = (gridDim.x * blockDim.x) >> 6;
    const int npairs = N >> 1;   // N even
    const int chunk = (npairs + nw - 1) / nw;
    const int p0 = wid * chunk;
    const int p1 = min(p0 + chunk, npairs);
    for (int p = p0; p < p1; ++p) {
        const int i = 2 * p + half;
        const int s0 = row_ptr[i];
        const int s1 = row_ptr[i + 1];
        const float di = dinv[i];
        float acc = di * x[(size_t)i * 32 + c];
        int e = s0;
        for (; e + 4 <= s1; e += 4) {
            int c0 = cols[e + 0];
            int c1 = cols[e + 1];
            int c2 = cols[e + 2];
            int c3 = cols[e + 3];
            float w0 = dinv[c0], w1 = dinv[c1], w2 = dinv[c2], w3 = dinv[c3];
            float v0 = x[(size_t)c0 * 32 + c];
            float v1 = x[(size_t)c1 * 32 + c];
            float v2 = x[(size_t)c2 * 32 + c];
            float v3 = x[(size_t)c3 * 32 + c];
            acc = fmaf(w0, v0, acc);
            acc = fmaf(w1, v1, acc);
            acc = fmaf(w2, v2, acc);
            acc = fmaf(w3, v3, acc);
        }
        for (; e < s1; ++e) {
            int cc = cols[e];
            acc = fmaf(dinv[cc], x[(size_t)cc * 32 + c], acc);
        }
        out[(size_t)i * 32 + c] = di * acc;
    }
}

// ---- MFMA GEMM, split-bf16 hi/lo. PRESCALE: scale A rows by dinv.
// BIASRELU: epilogue out = relu(C + bias[col]).
template <int IN_D, bool PRESCALE, bool BIASRELU>
__global__ __launch_bounds__(256, 2) void k_gemm_mfma(
        const float* __restrict__ in, const float* __restrict__ W,
        const float* __restrict__ dinv, const float* __restrict__ bias,
        float* __restrict__ out, int N) {
    constexpr int KT = IN_D / 32;
    const int lane = threadIdx.x & 63;
    const int wave = threadIdx.x >> 6;
    const int m = lane & 15;
    const int q = lane >> 4;

    bf16x8 Bhi[4][KT], Blo[4][KT];
#pragma unroll
    for (int nt = 0; nt < 4; ++nt) {
#pragma unroll
        for (int kt = 0; kt < KT; ++kt) {
#pragma unroll
            for (int j = 0; j < 8; ++j) {
                int k = kt * 32 + q * 8 + j;
                float w = W[k * 64 + nt * 16 + m];
                short hi = f2bf(w);
                Bhi[nt][kt][j] = hi;
                Blo[nt][kt][j] = f2bf(w - bf2f(hi));
            }
        }
    }

    const int tile = blockIdx.x * 4 + wave;
    const int node0 = tile * 16;
    if (node0 >= N) return;

    const float dv = PRESCALE ? dinv[node0 + m] : 1.0f;
    const float* rowp = in + (size_t)(node0 + m) * IN_D + q * 8;

    bf16x8 Ahi[KT], Alo[KT];
#pragma unroll
    for (int kt = 0; kt < KT; ++kt) {
        f32x4 a0 = *(const f32x4*)(rowp + kt * 32);
        f32x4 a1 = *(const f32x4*)(rowp + kt * 32 + 4);
#pragma unroll
        for (int j = 0; j < 4; ++j) {
            float xx = PRESCALE ? dv * a0[j] : a0[j];
            short hi = f2bf(xx);
            Ahi[kt][j] = hi;
            Alo[kt][j] = f2bf(xx - bf2f(hi));
        }
#pragma unroll
        for (int j = 0; j < 4; ++j) {
            float xx = PRESCALE ? dv * a1[j] : a1[j];
            short hi = f2bf(xx);
            Ahi[kt][4 + j] = hi;
            Alo[kt][4 + j] = f2bf(xx - bf2f(hi));
        }
    }

    f32x4 C[4];
#pragma unroll
    for (int nt = 0; nt < 4; ++nt) C[nt] = (f32x4){0.f, 0.f, 0.f, 0.f};

#pragma unroll
    for (int nt = 0; nt < 4; ++nt) {
#pragma unroll
        for (int kt = 0; kt < KT; ++kt) {
            C[nt] = __builtin_amdgcn_mfma_f32_16x16x32_bf16(Ahi[kt], Bhi[nt][kt], C[nt], 0, 0, 0);
            C[nt] = __builtin_amdgcn_mfma_f32_16x16x32_bf16(Ahi[kt], Blo[nt][kt], C[nt], 0, 0, 0);
            C[nt] = __builtin_amdgcn_mfma_f32_16x16x32_bf16(Alo[kt], Bhi[nt][kt], C[nt], 0, 0, 0);
        }
    }

    float br[4];
    if (BIASRELU) {
#pragma unroll
        for (int nt = 0; nt < 4; ++nt) br[nt] = bias[nt * 16 + m];
    }

    float* op = out + (size_t)node0 * 64;
#pragma unroll
    for (int nt = 0; nt < 4; ++nt) {
#pragma unroll
        for (int r = 0; r < 4; ++r) {
            int row = q * 4 + r;
            float v = C[nt][r];
            if (BIASRELU) v = fmaxf(v + br[nt], 0.0f);
            op[(size_t)row * 64 + nt * 16 + m] = v;
        }
    }
}

// ---- aggregation (layer 2): h[i] = relu( di*(M[i] + sum_j M[j]) + b ) ----
__global__ __launch_bounds__(256, 8) void k_agg(
        const float* __restrict__ M, const float* __restrict__ bias,
        const int* __restrict__ row_ptr, const int* __restrict__ cols,
        const float* __restrict__ dinv, float* __restrict__ out, int N) {
    const int lane = threadIdx.x & 63;
    int wid = (blockIdx.x * blockDim.x + threadIdx.x) >> 6;
    wid = __builtin_amdgcn_readfirstlane(wid);
    const int nw = (gridDim.x * blockDim.x) >> 6;
    const int chunk = (N + nw - 1) / nw;
    const int i0 = wid * chunk;
    const int i1 = min(i0 + chunk, N);
    const float b = bias[lane];

    for (int i = i0; i < i1; ++i) {
        const int s0 = row_ptr[i];
        const int s1 = row_ptr[i + 1];
        const float di = dinv[i];
        float acc = M[(size_t)i * 64 + lane];
        int e = s0;
        for (; e + 4 <= s1; e += 4) {
            int c0 = cols[e + 0];
            int c1 = cols[e + 1];
            int c2 = cols[e + 2];
            int c3 = cols[e + 3];
            float v0 = M[(size_t)c0 * 64 + lane];
            float v1 = M[(size_t)c1 * 64 + lane];
            float v2 = M[(size_t)c2 * 64 + lane];
            float v3 = M[(size_t)c3 * 64 + lane];
            acc += ((v0 + v1) + (v2 + v3));
        }
        for (; e < s1; ++e) {
            acc += M[(size_t)cols[e] * 64 + lane];
        }
        float h = fmaxf(fmaf(di, acc, b), 0.0f);
        out[(size_t)i * 64 + lane] = h;
    }
}

// ---- fused layer-3 agg + mean/max pool + meta encoder + fused assembly ----
__global__ __launch_bounds__(256, 8) void k_agg_pool(
        const float* __restrict__ M, const float* __restrict__ b3,
        const int* __restrict__ row_ptr, const int* __restrict__ cols,
        const float* __restrict__ dinv,
        const int* __restrict__ gstart, const int* __restrict__ gcnt,
        const float* __restrict__ metadata, const int* __restrict__ species,
        const float* __restrict__ emb, const float* __restrict__ Wm,
        const float* __restrict__ bm, float* __restrict__ fused, int G) {
    const int lane = threadIdx.x & 63;
    int wv = (blockIdx.x * blockDim.x + threadIdx.x) >> 6;
    wv = __builtin_amdgcn_readfirstlane(wv);
    const int nw = (gridDim.x * blockDim.x) >> 6;
    const float b = b3[lane];
    const float bmr = bm[lane];
    float wmr[16];
#pragma unroll
    for (int k = 0; k < 16; ++k) wmr[k] = Wm[k * 64 + lane];

    for (int g = wv; g < G; g += nw) {
        const int gs = gstart[g];
        const int gc = gcnt[g];
        float sum = 0.0f;
        float mx = -3.402823466e38f;
        for (int i = gs; i < gs + gc; ++i) {
            const int s0 = row_ptr[i];
            const int s1 = row_ptr[i + 1];
            const float di = dinv[i];
            float acc = M[(size_t)i * 64 + lane];
            int e = s0;
            for (; e + 4 <= s1; e += 4) {
                int c0 = cols[e + 0];
                int c1 = cols[e + 1];
                int c2 = cols[e + 2];
                int c3 = cols[e + 3];
                float v0 = M[(size_t)c0 * 64 + lane];
                float v1 = M[(size_t)c1 * 64 + lane];
                float v2 = M[(size_t)c2 * 64 + lane];
                float v3 = M[(size_t)c3 * 64 + lane];
                acc += ((v0 + v1) + (v2 + v3));
            }
            for (; e < s1; ++e) acc += M[(size_t)cols[e] * 64 + lane];
            float h = fmaxf(fmaf(di, acc, b), 0.0f);
            sum += h;
            mx = fmaxf(mx, h);
        }
        float mean = sum / fmaxf((float)gc, 1.0f);
        if (gc == 0) mx = 0.0f;
        float md = lane < 16 ? metadata[(size_t)g * 16 + lane] : 0.0f;
        float mval = bmr;
#pragma unroll
        for (int k = 0; k < 16; ++k) mval = fmaf(rlane(md, k), wmr[k], mval);
        mval = fmaxf(mval, 0.0f);
        const int sid = species[g];
        float* fr = fused + (size_t)g * 224;
        fr[lane] = mean;
        fr[64 + lane] = mx;
        fr[128 + lane] = mval;
        if (lane < 16) fr[192 + lane] = emb[(size_t)sid * 16 + lane];
        else if (lane < 32) fr[192 + lane] = 0.0f;
    }
}

// ---- MFMA predictor head: out = relu(fused @ Wp1 + bp1) @ Wp2 + bp2 ----
__global__ __launch_bounds__(256, 2) void k_pred_mfma(
        const float* __restrict__ fused, const float* __restrict__ Wp1,
        const float* __restrict__ bp1, const float* __restrict__ Wp2,
        const float* __restrict__ bp2, float* __restrict__ out, int G) {
    __shared__ __align__(16) short Whi[64 * 232];
    __shared__ __align__(16) short Wlo[64 * 232];
    const int t = threadIdx.x;
    for (int idx = t; idx < 64 * 232; idx += 256) {
        int n = idx / 232;
        int k = idx % 232;
        float w = (k < 208) ? Wp1[(size_t)k * 64 + n] : 0.0f;
        short hi = f2bf(w);
        Whi[n * 232 + k] = hi;
        Wlo[n * 232 + k] = f2bf(w - bf2f(hi));
    }
    __syncthreads();

    const int lane = t & 63;
    const int wave = t >> 6;
    const int m = lane & 15;
    const int q = lane >> 4;
    const int g0 = (blockIdx.x * 4 + wave) * 16;
    if (g0 >= G) return;

    const float* rowp = fused + (size_t)(g0 + m) * 224 + q * 8;

    f32x4 C[4];
#pragma unroll
    for (int nt = 0; nt < 4; ++nt) C[nt] = (f32x4){0.f, 0.f, 0.f, 0.f};

#pragma unroll
    for (int kt = 0; kt < 7; ++kt) {
        f32x4 a0 = *(const f32x4*)(rowp + kt * 32);
        f32x4 a1 = *(const f32x4*)(rowp + kt * 32 + 4);
        bf16x8 Ahi, Alo;
#pragma unroll
        for (int j = 0; j < 4; ++j) {
            short hi = f2bf(a0[j]);
            Ahi[j] = hi;
            Alo[j] = f2bf(a0[j] - bf2f(hi));
        }
#pragma unroll
        for (int j = 0; j < 4; ++j) {
            short hi = f2bf(a1[j]);
            Ahi[4 + j] = hi;
            Alo[4 + j] = f2bf(a1[j] - bf2f(hi));
        }
#pragma unroll
        for (int nt = 0; nt < 4; ++nt) {
            const int boff = (nt * 16 + m) * 232 + kt * 32 + q * 8;
            bf16x8 Bh = *(const bf16x8*)&Whi[boff];
            bf16x8 Bl = *(const bf16x8*)&Wlo[boff];
            C[nt] = __builtin_amdgcn_mfma_f32_16x16x32_bf16(Ahi, Bh, C[nt], 0, 0, 0);
            C[nt] = __builtin_amdgcn_mfma_f32_16x16x32_bf16(Ahi, Bl, C[nt], 0, 0, 0);
            C[nt] = __builtin_amdgcn_mfma_f32_16x16x32_bf16(Alo, Bh, C[nt], 0, 0, 0);
        }
    }

    float wp2r[4], bp1r[4];
#pragma unroll
    for (int nt = 0; nt < 4; ++nt) {
        wp2r[nt] = Wp2[nt * 16 + m];
        bp1r[nt] = bp1[nt * 16 + m];
    }
    const float bp2v = bp2[0];
    float s[4];
#pragma unroll
    for (int r = 0; r < 4; ++r) {
        float acc = 0.0f;
#pragma unroll
        for (int nt = 0; nt < 4; ++nt)
            acc += fmaxf(C[nt][r] + bp1r[nt], 0.0f) * wp2r[nt];
        s[r] = acc;
    }
#pragma unroll
    for (int off = 1; off < 16; off <<= 1) {
#pragma unroll
        for (int r = 0; r < 4; ++r) s[r] += __shfl_xor(s[r], off);
    }
    if (m == 0) {
#pragma unroll
        for (int r = 0; r < 4; ++r) out[g0 + q * 4 + r] = s[r] + bp2v;
    }
}

extern "C" void kernel_launch(void* const* d_in, const int* in_sizes, int n_in,
                              void* d_out, int out_size, void* d_ws, size_t ws_size,
                              hipStream_t stream) {
    const int N = N_NODES, E = N_EDGES, G = N_GRAPHS;
    const int NT = N + G;

    const float* x        = (const float*)d_in[0];
    const float* metadata = (const float*)d_in[1];
    const int*   ei       = (const int*)d_in[2];
    const int*   batch    = (const int*)d_in[3];
    const int*   species  = (const int*)d_in[4];
    const float* W1 = (const float*)d_in[5];
    const float* b1 = (const float*)d_in[6];
    const float* W2 = (const float*)d_in[7];
    const float* b2 = (const float*)d_in[8];
    const float* W3 = (const float*)d_in[9];
    const float* b3 = (const float*)d_in[10];
    const float* Wm = (const float*)d_in[11];
    const float* bm = (const float*)d_in[12];
    const float* emb = (const float*)d_in[13];
    const float* Wp1 = (const float*)d_in[14];
    const float* bp1 = (const float*)d_in[15];
    const float* Wp2 = (const float*)d_in[16];
    const float* bp2 = (const float*)d_in[17];
    float* out = (float*)d_out;

    char* ws = (char*)d_ws;
    size_t off = 0;
    auto alloc = [&](size_t bytes) -> void* {
        void* p = ws + off;
        off = (off + bytes + 255) & ~(size_t)255;
        return p;
    };
    int*   cnt     = (int*)alloc((size_t)NT * 4);
    int*   row_ptr = (int*)alloc((size_t)(N + 1) * 4);
    int*   cursor  = (int*)alloc((size_t)N * 4);
    float* dinv    = (float*)alloc((size_t)N * 4);
    int*   gstart  = (int*)alloc((size_t)G * 4);
    int*   bsum    = (int*)alloc(2048 * 4);
    int*   boffs   = (int*)alloc(2048 * 4);
    int*   bcur    = (int*)alloc((size_t)NBKT * 4);
    int*   colsS   = (int*)alloc((size_t)E * 4);
    float* hA      = (float*)alloc((size_t)N * 64 * 4);
    float* hB      = (float*)alloc((size_t)N * 64 * 4);
    float* fused   = (float*)alloc((size_t)G * 224 * 4);

    int* degcnt = cnt;
    int* gcnt = cnt + N;
    int2* tmp = (int2*)hA;        // aliases hA: dead until first GEMM writes it

    const int nbE = (E + 255) / 256;    // 6250
    const int nbT = (NT + 255) / 256;   // 1627
    const int nbG = (N / 16 + 3) / 4;   // 6250 blocks, 4 tiles each

    hipMemsetAsync(cnt, 0, (size_t)NT * 4, stream);

    k_hist<<<nbE, 256, 0, stream>>>(ei, batch, degcnt, gcnt, E, N);
    k_scan_blocksum<<<nbT, 256, 0, stream>>>(cnt, bsum, NT);
    k_scan_single<<<1, 256, 0, stream>>>(bsum, boffs, nbT);
    k_scan_final<<<nbT, 256, 0, stream>>>(cnt, boffs, row_ptr, cursor, dinv, gstart,
                                          bcur, NT, N, E);
    // two-phase CSR scatter (write-combining friendly)
    k_bin<<<(E + BIN_CHUNK - 1) / BIN_CHUNK, 256, 0, stream>>>(ei, ei + E, bcur, tmp, E);
    k_scat2<<<NBKT, 256, 0, stream>>>(tmp, row_ptr, cursor, colsS, N);

    // layer 1 (reordered): xa = Dinv(A+I)Dinv x, then h1 = relu(xa@W1 + b1)
    k_agg32<<<4096, 256, 0, stream>>>(x, row_ptr, colsS, dinv, hB, N);
    k_gemm_mfma<32, false, true><<<nbG, 256, 0, stream>>>(hB, W1, dinv, b1, hA, N);
    // layer 2
    k_gemm_mfma<64, true, false><<<nbG, 256, 0, stream>>>(hA, W2, dinv, b2, hB, N);
    k_agg<<<4096, 256, 0, stream>>>(hB, b2, row_ptr, colsS, dinv, hA, N);
    // layer 3 GEMM, then fused agg+pool+meta+assembly
    k_gemm_mfma<64, true, false><<<nbG, 256, 0, stream>>>(hA, W3, dinv, b3, hB, N);
    k_agg_pool<<<2048, 256, 0, stream>>>(hB, b3, row_ptr, colsS, dinv, gstart, gcnt,
                                         metadata, species, emb, Wm, bm, fused, G);

    // predictor head (MFMA)
    k_pred_mfma<<<(G / 16 + 3) / 4, 256, 0, stream>>>(fused, Wp1, bp1, Wp2, bp2, out, G);
}